// Round 18
// baseline (415.841 us; speedup 1.0000x reference)
//
#include <hip/hip_runtime.h>

#define N_NODES 50000
#define N_EDGES 800000
#define N_GRAPH 1000
#define EPAD (N_EDGES + 8 * N_NODES)   // padded CSR capacity

typedef short bf16x8 __attribute__((ext_vector_type(8)));
typedef float f32x4 __attribute__((ext_vector_type(4)));

__device__ inline short f2b(float f) {   // f32 -> bf16 (RNE)
    union { float f; unsigned u; } x; x.f = f;
    unsigned r = x.u + 0x7FFF + ((x.u >> 16) & 1);
    return (short)(r >> 16);
}
__device__ inline float b2f_lo(unsigned v) {
    union { unsigned u; float f; } x; x.u = v << 16; return x.f;
}
__device__ inline float b2f_hi(unsigned v) {
    union { unsigned u; float f; } x; x.u = v & 0xFFFF0000u; return x.f;
}
__device__ inline float b2f_s(short s) {
    union { unsigned u; float f; } x; x.u = ((unsigned)(unsigned short)s) << 16; return x.f;
}
__device__ inline unsigned pack2(short lo, short hi) {
    return ((unsigned)(unsigned short)lo) | (((unsigned)(unsigned short)hi) << 16);
}

// ---------------- W[128(k)][128(c)] f32 -> WbT[c][k] bf16 (all 3 layers, one launch) ----------------
__global__ void wbt3_k(const float* __restrict__ W0, const float* __restrict__ W1,
                       const float* __restrict__ W2, short* __restrict__ wbt) {
    int l = blockIdx.x >> 6;                    // 64 blocks per layer
    const float* W = (l == 0) ? W0 : (l == 1) ? W1 : W2;
    int idx = (blockIdx.x & 63) * 256 + threadIdx.x;   // 0..16383
    int k = idx >> 7, c = idx & 127;
    wbt[(size_t)l * 16384 + (size_t)c * 128 + k] = f2b(W[idx]);
}

// ---------------- aeW for all 3 layers ----------------
__global__ void aew3_k(const float* __restrict__ We0, const float* __restrict__ ae0,
                       const float* __restrict__ We1, const float* __restrict__ ae1,
                       const float* __restrict__ We2, const float* __restrict__ ae2,
                       float* __restrict__ aeW3) {
    const float* We = (blockIdx.x == 0) ? We0 : (blockIdx.x == 1) ? We1 : We2;
    const float* ae = (blockIdx.x == 0) ? ae0 : (blockIdx.x == 1) ? ae1 : ae2;
    int t = threadIdx.x;   // 128
    int k = t >> 3, h = t & 7;
    float s = 0.f;
#pragma unroll
    for (int c = 0; c < 16; c++) s += We[k * 128 + h * 16 + c] * ae[h * 16 + c];
    aeW3[blockIdx.x * 128 + t] = s;
}

// ---------------- layer GEMM via MFMA + fused node_al epilogue ----------------
// Fragment cols c = wc + fn*16 + lr: each fn is one head (h = (wid&1)*4+fn), lr spans
// its 16 channels -> per-row head-dots reduce over the 4 low lane bits via shfl_xor.
template <bool AF32>
__global__ __launch_bounds__(256) void gemm_mfma(const void* __restrict__ Aptr,
                                                 const short* __restrict__ WbT,
                                                 const float* __restrict__ a_s,
                                                 const float* __restrict__ a_d,
                                                 short* __restrict__ outb,
                                                 float* __restrict__ alsrc,
                                                 float* __restrict__ aldst, int nrows) {
    const int tid = threadIdx.x;
    const int n0 = blockIdx.x * 64;
    const int wid = tid >> 6, lane = tid & 63;
    const int lr = lane & 15, kg = lane >> 4;
    const int wr = (wid >> 1) * 32;
    const int wc = (wid & 1) * 64;

    f32x4 acc[2][4] = {};

#pragma unroll
    for (int ks = 0; ks < 4; ks++) {
        const int k0 = ks * 32;
        bf16x8 a[2], b[4];
#pragma unroll
        for (int fm = 0; fm < 2; fm++) {
            int gr = n0 + wr + fm * 16 + lr;
            bf16x8 v = {};
            if (gr < nrows) {
                if (AF32) {
                    const float* ap = (const float*)Aptr + (size_t)gr * 128 + k0 + kg * 8;
                    float4 f0 = *(const float4*)(ap);
                    float4 f1 = *(const float4*)(ap + 4);
                    v[0] = f2b(f0.x); v[1] = f2b(f0.y); v[2] = f2b(f0.z); v[3] = f2b(f0.w);
                    v[4] = f2b(f1.x); v[5] = f2b(f1.y); v[6] = f2b(f1.z); v[7] = f2b(f1.w);
                } else {
                    v = *(const bf16x8*)((const short*)Aptr + (size_t)gr * 128 + k0 + kg * 8);
                }
            }
            a[fm] = v;
        }
#pragma unroll
        for (int fn = 0; fn < 4; fn++)
            b[fn] = *(const bf16x8*)(WbT + (size_t)(wc + fn * 16 + lr) * 128 + k0 + kg * 8);
#pragma unroll
        for (int fm = 0; fm < 2; fm++)
#pragma unroll
            for (int fn = 0; fn < 4; fn++)
                acc[fm][fn] = __builtin_amdgcn_mfma_f32_16x16x32_bf16(
                    a[fm], b[fn], acc[fm][fn], 0, 0, 0);
    }

    // attention coefficients for this thread's 4 (head, channel) slots
    float asc[4], adc[4];
#pragma unroll
    for (int fn = 0; fn < 4; fn++) {
        int c = wc + fn * 16 + lr;   // == h*16 + lr
        asc[fn] = a_s[c];
        adc[fn] = a_d[c];
    }

#pragma unroll
    for (int fm = 0; fm < 2; fm++) {
#pragma unroll
        for (int r = 0; r < 4; r++) {
            int gr = n0 + wr + fm * 16 + kg * 4 + r;
            float ps[4], pd[4];
#pragma unroll
            for (int fn = 0; fn < 4; fn++) {
                float z = acc[fm][fn][r];
                ps[fn] = z * asc[fn];
                pd[fn] = z * adc[fn];
            }
            if (gr < nrows) {
#pragma unroll
                for (int fn = 0; fn < 4; fn++)
                    outb[(size_t)gr * 128 + wc + fn * 16 + lr] = f2b(acc[fm][fn][r]);
            }
#pragma unroll
            for (int off = 1; off < 16; off <<= 1) {
#pragma unroll
                for (int fn = 0; fn < 4; fn++) {
                    ps[fn] += __shfl_xor(ps[fn], off);
                    pd[fn] += __shfl_xor(pd[fn], off);
                }
            }
            if (lr == 0 && gr < nrows) {
                *(float4*)(alsrc + (size_t)gr * 8 + (wid & 1) * 4) =
                    make_float4(ps[0], ps[1], ps[2], ps[3]);
                *(float4*)(aldst + (size_t)gr * 8 + (wid & 1) * 4) =
                    make_float4(pd[0], pd[1], pd[2], pd[3]);
            }
        }
    }
}

// ---------------- CSR build (padded to multiples of 8 per dst) ----------------
__global__ void hist_k(const int* __restrict__ ei, int* __restrict__ cnt, int ne) {
    int e = blockIdx.x * blockDim.x + threadIdx.x;
    if (e < ne) atomicAdd(&cnt[ei[ne + e]], 1);
}

__global__ void scan1_k(const int* __restrict__ cnt, int* __restrict__ rowptr,
                        int* __restrict__ part, int n) {
    __shared__ int s[256];
    int tid = threadIdx.x;
    int i = blockIdx.x * 256 + tid;
    int v = (i < n) ? ((cnt[i] + 7) & ~7) : 0;   // padded count
    s[tid] = v; __syncthreads();
#pragma unroll
    for (int off = 1; off < 256; off <<= 1) {
        int t = (tid >= off) ? s[tid - off] : 0;
        __syncthreads();
        s[tid] += t;
        __syncthreads();
    }
    if (i < n) rowptr[i] = s[tid] - v;
    if (tid == 255) part[blockIdx.x] = s[255];
}

__global__ void scan2_k(int* __restrict__ part, int npart) {
    __shared__ int s[256];
    int tid = threadIdx.x;
    int v = (tid < npart) ? part[tid] : 0;
    s[tid] = v; __syncthreads();
#pragma unroll
    for (int off = 1; off < 256; off <<= 1) {
        int t = (tid >= off) ? s[tid - off] : 0;
        __syncthreads();
        s[tid] += t;
        __syncthreads();
    }
    if (tid < npart) part[tid] = s[tid] - v;
}

__global__ void scan3_k(int* __restrict__ rowptr, const int* __restrict__ part,
                        const int* __restrict__ cnt, int* __restrict__ cursor, int n) {
    int i = blockIdx.x * 256 + threadIdx.x;
    if (i < n) {
        int r = rowptr[i] + part[blockIdx.x];
        rowptr[i] = r;
        cursor[i] = r;
        if (i == n - 1) rowptr[n] = r + ((cnt[i] + 7) & ~7);
    }
}

// scatter: build csr_src + CSR-ordered bf16 edge attrs (pads remain 0x80808080 from memset)
__global__ void scatter_k(const int* __restrict__ ei, const float* __restrict__ eattr,
                          int* __restrict__ cursor, int* __restrict__ csr_src,
                          short* __restrict__ eatb, int ne) {
    int e = blockIdx.x * blockDim.x + threadIdx.x;
    if (e >= ne) return;
    int d = ei[ne + e];
    int p = atomicAdd(&cursor[d], 1);
    csr_src[p] = ei[e];
    const float4* ep = (const float4*)(eattr + (size_t)e * 16);
    short* op = eatb + (size_t)p * 16;
#pragma unroll
    for (int q = 0; q < 4; q++) {
        float4 v = ep[q];
        *(short4*)(op + q * 4) = make_short4(f2b(v.x), f2b(v.y), f2b(v.z), f2b(v.w));
    }
}

// ---------------- graph boundaries from sorted batch ----------------
__global__ void gbound_k(const int* __restrict__ batch, int* __restrict__ gb, int n, int g) {
    int i = blockIdx.x * 256 + threadIdx.x;
    if (i >= n) return;
    int b1 = batch[i];
    int b0 = (i == 0) ? -1 : batch[i - 1];
    for (int q = b0 + 1; q <= b1; q++) gb[q] = i;
    if (i == n - 1)
        for (int q = b1 + 1; q <= g; q++) gb[q] = n;
}

// ---------------- segmented pool: one block per graph (sorted batch), bf16 out ----------------
__global__ __launch_bounds__(256) void pools_k(const short* __restrict__ h3b,
                                               const int* __restrict__ gb,
                                               short* __restrict__ poolb) {
    __shared__ float red[128];
    int g = blockIdx.x;
    int c = threadIdx.x & 127;
    int par = threadIdx.x >> 7;   // 0/1
    int i0 = gb[g], i1 = gb[g + 1];
    float s = 0.f;
    for (int i = i0 + par; i < i1; i += 2) s += b2f_s(h3b[(size_t)i * 128 + c]);
    if (par == 1) red[c] = s;
    __syncthreads();
    if (par == 0) poolb[(size_t)g * 128 + c] = f2b(s + red[c]);
}

// ---------------- gather: fused logits + softmax-aggregate; producer-side exp ----------------
__global__ __launch_bounds__(256) void gather_k(const int* __restrict__ rowptr,
                                                const int* __restrict__ csr_src,
                                                const short* __restrict__ eatb,
                                                const float* __restrict__ aeW,
                                                const float* __restrict__ alsrc,
                                                const float* __restrict__ aldst,
                                                const short* __restrict__ xsb,
                                                const float* __restrict__ b,
                                                short* __restrict__ houtb, int n) {
    __shared__ float sAe[128];
    if (threadIdx.x < 128) sAe[threadIdx.x] = aeW[threadIdx.x];
    __syncthreads();
    int dst = blockIdx.x * 4 + (threadIdx.x >> 6);
    if (dst >= n) return;
    const int lane = threadIdx.x & 63;
    const int h  = lane >> 3;   // consumer head
    const int pe = lane >> 3;   // producer edge
    const int ph = lane & 7;    // producer head
    const float L2E = 1.44269504f;
    int p0 = rowptr[dst], p1 = rowptr[dst + 1];
    float ald_p = aldst[dst * 8 + ph];   // producer-role dst coefficient
    float den = 0.f, acc0 = 0.f, acc1 = 0.f;
    const int nfull = (p1 - p0) >> 3;   // padded: no tail
    int p = p0;
    int svo = 0; unsigned w = 0;
    if (nfull > 0) {
        svo = csr_src[p + pe];
        w = *(const unsigned*)(eatb + (size_t)(p + pe) * 16 + ph * 2);
    }
    for (int c = 0; c < nfull; c++) {
        int csv = svo; unsigned cw = w;
        int pn = p + 8;
        if (c + 1 < nfull) {                         // prefetch next chunk
            svo = csr_src[pn + pe];
            w = *(const unsigned*)(eatb + (size_t)(pn + pe) * 16 + ph * 2);
        }
        // ---- producer: finished exp weight for (edge pe, head ph) ----
        int sc = csv < 0 ? 0 : csv;
        float pal = alsrc[sc * 8 + ph];
#pragma unroll
        for (int k = 0; k < 8; k++) {
            unsigned u = __shfl(cw, pe * 8 + k);
            pal += b2f_lo(u) * sAe[k * 16 + ph] + b2f_hi(u) * sAe[k * 16 + 8 + ph];
        }
        float lg = pal + ald_p;
        lg = lg > 0.f ? lg : 0.2f * lg;              // leaky_relu(0.2)
        float pex = exp2f(lg * L2E);
        if (csv < 0) pex = 0.f;                      // pad edge contributes nothing
        // ---- rows ----
        int t0 = __shfl(csv, 0),  t1 = __shfl(csv, 8),  t2 = __shfl(csv, 16), t3 = __shfl(csv, 24);
        int t4 = __shfl(csv, 32), t5 = __shfl(csv, 40), t6 = __shfl(csv, 48), t7 = __shfl(csv, 56);
        t0 = t0 < 0 ? 0 : t0;  t1 = t1 < 0 ? 0 : t1;
        t2 = t2 < 0 ? 0 : t2;  t3 = t3 < 0 ? 0 : t3;
        t4 = t4 < 0 ? 0 : t4;  t5 = t5 < 0 ? 0 : t5;
        t6 = t6 < 0 ? 0 : t6;  t7 = t7 < 0 ? 0 : t7;
        unsigned v0 = *(const unsigned*)(xsb + (size_t)t0 * 128 + lane * 2);
        unsigned v1 = *(const unsigned*)(xsb + (size_t)t1 * 128 + lane * 2);
        unsigned v2 = *(const unsigned*)(xsb + (size_t)t2 * 128 + lane * 2);
        unsigned v3 = *(const unsigned*)(xsb + (size_t)t3 * 128 + lane * 2);
        unsigned v4 = *(const unsigned*)(xsb + (size_t)t4 * 128 + lane * 2);
        unsigned v5 = *(const unsigned*)(xsb + (size_t)t5 * 128 + lane * 2);
        unsigned v6 = *(const unsigned*)(xsb + (size_t)t6 * 128 + lane * 2);
        unsigned v7 = *(const unsigned*)(xsb + (size_t)t7 * 128 + lane * 2);
        unsigned vv[8] = {v0, v1, v2, v3, v4, v5, v6, v7};
        // ---- consumer: weighted accumulate with ready weights ----
#pragma unroll
        for (int i = 0; i < 8; i++) {
            float ex = __shfl(pex, i * 8 + h);
            den  += ex;
            acc0 += b2f_lo(vv[i]) * ex;
            acc1 += b2f_hi(vv[i]) * ex;
        }
        p = pn;
    }
    float inv = 1.f / (den + 1e-16f);
    const float2 bb = *(const float2*)(b + lane * 2);
    unsigned o = pack2(f2b(acc0 * inv + bb.x), f2b(acc1 * inv + bb.y));
    *(unsigned*)(houtb + (size_t)dst * 128 + lane * 2) = o;
}

// ---------------- Wl1 [512(k),512(c)] f32 -> Wl1T [c][k] bf16 ----------------
__global__ void wl1t_k(const float* __restrict__ Wl1, short* __restrict__ Wl1T) {
    int idx = blockIdx.x * blockDim.x + threadIdx.x;   // 262144
    int k = idx >> 9, c = idx & 511;
    Wl1T[(size_t)c * 512 + k] = f2b(Wl1[idx]);
}

__global__ void init_out(float* __restrict__ out, const float* __restrict__ bl2, int n) {
    int t = blockIdx.x * blockDim.x + threadIdx.x;
    if (t < n) out[t] = bl2[0];
}

// ---------------- fused final MLP via bf16 MFMA: BK=128 double-buffer ----------------
__global__ __launch_bounds__(256) void final_mfma(
    const short* __restrict__ h1, const short* __restrict__ h2,
    const short* __restrict__ h3, const short* __restrict__ poolb,
    const int* __restrict__ batch, const short* __restrict__ Wl1T,
    const float* __restrict__ bl1, const float* __restrict__ Wl2,
    float* __restrict__ out, int nrows)
{
    __shared__ short Abuf[2][16 * 64 * 8];   // 2 x 16 KB: [buf][slot][row-lane][8]
    __shared__ int   sBatch[64];
    const int tid = threadIdx.x;
    const int n0 = blockIdx.x * 64;
    const int j0 = blockIdx.y * 256;
    const int wid = tid >> 6, lane = tid & 63;
    const int lr = lane & 15, kg = lane >> 4;

    if (tid < 64) {
        int gr = n0 + tid;
        sBatch[tid] = (gr < nrows) ? batch[gr] : 0;
    }
    __syncthreads();

    const short* seg_base[4] = {h1, h2, h3, poolb};

    auto STAGE = [&](int t) {
        const short* base = seg_base[t];
        int gr = n0 + lane;
        int grow = (t == 3) ? sBatch[lane] : ((gr < nrows) ? gr : 0);
        const short* rowp = base + (size_t)grow * 128;
#pragma unroll
        for (int q = 0; q < 4; q++) {
            const short* src = rowp + q * 32 + wid * 8;
#if __has_builtin(__builtin_amdgcn_global_load_lds)
            __builtin_amdgcn_global_load_lds(
                (const __attribute__((address_space(1))) unsigned int*)src,
                (__attribute__((address_space(3))) unsigned int*)
                    &Abuf[t & 1][((q * 4 + wid) * 64 + lane) * 8],
                16, 0, 0);
#else
            uint4 v = *(const uint4*)src;
            *(uint4*)(&Abuf[t & 1][((q * 4 + wid) * 64 + lane) * 8]) = v;
#endif
        }
    };

    f32x4 acc[4][4] = {};

    STAGE(0);
    __syncthreads();   // segment 0 landed (full drain)
#pragma unroll
    for (int t = 0; t < 4; t++) {
        if (t < 3) STAGE(t + 1);   // hides under this segment's 64 MFMAs
#pragma unroll
        for (int ks = 0; ks < 4; ks++) {
            bf16x8 a[4], b[4];
#pragma unroll
            for (int fn = 0; fn < 4; fn++)
                b[fn] = *(const bf16x8*)(Wl1T + (size_t)(j0 + wid * 64 + fn * 16 + lr) * 512
                                         + t * 128 + ks * 32 + kg * 8);
#pragma unroll
            for (int fm = 0; fm < 4; fm++)
                a[fm] = *(const bf16x8*)(&Abuf[t & 1][((ks * 4 + kg) * 64 + fm * 16 + lr) * 8]);
#pragma unroll
            for (int fm = 0; fm < 4; fm++)
#pragma unroll
                for (int fn = 0; fn < 4; fn++)
                    acc[fm][fn] = __builtin_amdgcn_mfma_f32_16x16x32_bf16(
                        a[fm], b[fn], acc[fm][fn], 0, 0, 0);
        }
        if (t < 3) __syncthreads();   // drains STAGE(t+1); buffer reads done
    }

    float w2[4], b1c[4];
#pragma unroll
    for (int fn = 0; fn < 4; fn++) {
        int c = j0 + wid * 64 + fn * 16 + lr;
        w2[fn]  = Wl2[c];
        b1c[fn] = bl1[c];
    }

#pragma unroll
    for (int fm = 0; fm < 4; fm++) {
#pragma unroll
        for (int r = 0; r < 4; r++) {
            float s = 0.f;
#pragma unroll
            for (int fn = 0; fn < 4; fn++) {
                float z = acc[fm][fn][r] + b1c[fn];
                z = z > 0.f ? z : 0.01f * z;
                s += z * w2[fn];
            }
            s += __shfl_xor(s, 1);
            s += __shfl_xor(s, 2);
            s += __shfl_xor(s, 4);
            s += __shfl_xor(s, 8);
            if (lr == 0) {
                int gr = n0 + fm * 16 + kg * 4 + r;
                if (gr < nrows) atomicAdd(out + gr, s);
            }
        }
    }
}

extern "C" void kernel_launch(void* const* d_in, const int* in_sizes, int n_in,
                              void* d_out, int out_size, void* d_ws, size_t ws_size,
                              hipStream_t stream) {
    const float* x     = (const float*)d_in[0];
    const int*   ei    = (const int*)d_in[1];
    const float* eattr = (const float*)d_in[2];
    const int*   batch = (const int*)d_in[3];
    const float* W[3]   = {(const float*)d_in[4],  (const float*)d_in[10], (const float*)d_in[16]};
    const float* We[3]  = {(const float*)d_in[5],  (const float*)d_in[11], (const float*)d_in[17]};
    const float* as_[3] = {(const float*)d_in[6],  (const float*)d_in[12], (const float*)d_in[18]};
    const float* ad_[3] = {(const float*)d_in[7],  (const float*)d_in[13], (const float*)d_in[19]};
    const float* ae_[3] = {(const float*)d_in[8],  (const float*)d_in[14], (const float*)d_in[20]};
    const float* b_[3]  = {(const float*)d_in[9],  (const float*)d_in[15], (const float*)d_in[21]};
    const float* Wl1 = (const float*)d_in[22];
    const float* bl1 = (const float*)d_in[23];
    const float* Wl2 = (const float*)d_in[24];
    const float* bl2 = (const float*)d_in[25];

    const int N = N_NODES, E = N_EDGES, G = N_GRAPH;

    float* ws    = (float*)d_ws;
    float* alsrc = ws;                          // N*8
    float* aldst = alsrc + (size_t)N * 8;       // N*8
    float* aeW3  = aldst + (size_t)N * 8;       // 3*128
    short* xsb   = (short*)(aeW3 + 384);        // N*128 bf16 (layer GEMM out)
    short* hb0   = xsb + (size_t)N * 128;       // N*128 bf16
    short* hb1   = hb0 + (size_t)N * 128;
    short* hb2   = hb1 + (size_t)N * 128;
    short* hb[3] = {hb0, hb1, hb2};
    short* poolb = hb2 + (size_t)N * 128;       // G*128 bf16
    short* wbt   = poolb + (size_t)G * 128;     // 3 x 128*128 bf16
    short* wl1t  = wbt + 3 * 16384;             // 512*512 bf16
    short* eatb  = wl1t + 262144;               // EPAD*16 bf16
    int*   cnt     = (int*)(eatb + (size_t)EPAD * 16);  // N
    int*   rowptr  = cnt + N;                   // N+1
    int*   cursor  = rowptr + N + 1;            // N
    int*   part    = cursor + N;                // 256
    int*   gb      = part + 256;                // G+1
    int*   csr_src = gb + G + 1;                // EPAD

    // ---- once per call: bf16 conversions + padded dst-CSR + graph bounds ----
    wbt3_k<<<192, 256, 0, stream>>>(W[0], W[1], W[2], wbt);
    wl1t_k<<<1024, 256, 0, stream>>>(Wl1, wl1t);
    aew3_k<<<3, 128, 0, stream>>>(We[0], ae_[0], We[1], ae_[1], We[2], ae_[2], aeW3);
    hipMemsetAsync(cnt, 0, (size_t)N * sizeof(int), stream);
    hipMemsetAsync(csr_src, 0x80, (size_t)EPAD * sizeof(int), stream);  // pads negative
    hist_k<<<(E + 255) / 256, 256, 0, stream>>>(ei, cnt, E);
    const int nblk = (N + 255) / 256;   // 196
    scan1_k<<<nblk, 256, 0, stream>>>(cnt, rowptr, part, N);
    scan2_k<<<1, 256, 0, stream>>>(part, nblk);
    scan3_k<<<nblk, 256, 0, stream>>>(rowptr, part, cnt, cursor, N);
    scatter_k<<<(E + 255) / 256, 256, 0, stream>>>(ei, eattr, cursor, csr_src, eatb, E);
    gbound_k<<<nblk, 256, 0, stream>>>(batch, gb, N, G);

    for (int l = 0; l < 3; l++) {
        if (l == 0)
            gemm_mfma<true><<<(N + 63) / 64, 256, 0, stream>>>(
                x, wbt, as_[0], ad_[0], xsb, alsrc, aldst, N);
        else
            gemm_mfma<false><<<(N + 63) / 64, 256, 0, stream>>>(
                hb[l - 1], wbt + l * 16384, as_[l], ad_[l], xsb, alsrc, aldst, N);
        gather_k<<<(N + 3) / 4, 256, 0, stream>>>(rowptr, csr_src, eatb, aeW3 + l * 128,
                                                  alsrc, aldst, xsb, b_[l], hb[l], N);
    }
    pools_k<<<G, 256, 0, stream>>>(hb[2], gb, poolb);

    init_out<<<(N + 255) / 256, 256, 0, stream>>>((float*)d_out, bl2, N);
    dim3 fg((N + 63) / 64, 2);
    final_mfma<<<fg, 256, 0, stream>>>(hb[0], hb[1], hb[2], poolb, batch,
                                       wl1t, bl1, Wl2, (float*)d_out, N);
}

// Round 19
// 402.179 us; speedup vs baseline: 1.0340x; 1.0340x over previous
//
#include <hip/hip_runtime.h>

#define N_NODES 50000
#define N_EDGES 800000
#define N_GRAPH 1000
#define EPAD (N_EDGES + 8 * N_NODES)   // padded CSR capacity

typedef short bf16x8 __attribute__((ext_vector_type(8)));
typedef float f32x4 __attribute__((ext_vector_type(4)));

__device__ inline short f2b(float f) {   // f32 -> bf16 (RNE)
    union { float f; unsigned u; } x; x.f = f;
    unsigned r = x.u + 0x7FFF + ((x.u >> 16) & 1);
    return (short)(r >> 16);
}
__device__ inline float b2f_lo(unsigned v) {
    union { unsigned u; float f; } x; x.u = v << 16; return x.f;
}
__device__ inline float b2f_hi(unsigned v) {
    union { unsigned u; float f; } x; x.u = v & 0xFFFF0000u; return x.f;
}
__device__ inline float b2f_s(short s) {
    union { unsigned u; float f; } x; x.u = ((unsigned)(unsigned short)s) << 16; return x.f;
}
__device__ inline unsigned pack2(short lo, short hi) {
    return ((unsigned)(unsigned short)lo) | (((unsigned)(unsigned short)hi) << 16);
}

// ---------------- W[128(k)][128(c)] f32 -> WbT[c][k] bf16 (all 3 layers, one launch) ----------------
__global__ void wbt3_k(const float* __restrict__ W0, const float* __restrict__ W1,
                       const float* __restrict__ W2, short* __restrict__ wbt) {
    int l = blockIdx.x >> 6;                    // 64 blocks per layer
    const float* W = (l == 0) ? W0 : (l == 1) ? W1 : W2;
    int idx = (blockIdx.x & 63) * 256 + threadIdx.x;   // 0..16383
    int k = idx >> 7, c = idx & 127;
    wbt[(size_t)l * 16384 + (size_t)c * 128 + k] = f2b(W[idx]);
}

// ---------------- aeW for all 3 layers ----------------
__global__ void aew3_k(const float* __restrict__ We0, const float* __restrict__ ae0,
                       const float* __restrict__ We1, const float* __restrict__ ae1,
                       const float* __restrict__ We2, const float* __restrict__ ae2,
                       float* __restrict__ aeW3) {
    const float* We = (blockIdx.x == 0) ? We0 : (blockIdx.x == 1) ? We1 : We2;
    const float* ae = (blockIdx.x == 0) ? ae0 : (blockIdx.x == 1) ? ae1 : ae2;
    int t = threadIdx.x;   // 128
    int k = t >> 3, h = t & 7;
    float s = 0.f;
#pragma unroll
    for (int c = 0; c < 16; c++) s += We[k * 128 + h * 16 + c] * ae[h * 16 + c];
    aeW3[blockIdx.x * 128 + t] = s;
}

// ---------------- layer GEMM via MFMA (A dtype templated); bf16 out ----------------
template <bool AF32>
__global__ __launch_bounds__(256) void gemm_mfma(const void* __restrict__ Aptr,
                                                 const short* __restrict__ WbT,
                                                 short* __restrict__ outb, int nrows) {
    const int tid = threadIdx.x;
    const int n0 = blockIdx.x * 64;
    const int wid = tid >> 6, lane = tid & 63;
    const int lr = lane & 15, kg = lane >> 4;
    const int wr = (wid >> 1) * 32;
    const int wc = (wid & 1) * 64;

    f32x4 acc[2][4] = {};

#pragma unroll
    for (int ks = 0; ks < 4; ks++) {
        const int k0 = ks * 32;
        bf16x8 a[2], b[4];
#pragma unroll
        for (int fm = 0; fm < 2; fm++) {
            int gr = n0 + wr + fm * 16 + lr;
            bf16x8 v = {};
            if (gr < nrows) {
                if (AF32) {
                    const float* ap = (const float*)Aptr + (size_t)gr * 128 + k0 + kg * 8;
                    float4 f0 = *(const float4*)(ap);
                    float4 f1 = *(const float4*)(ap + 4);
                    v[0] = f2b(f0.x); v[1] = f2b(f0.y); v[2] = f2b(f0.z); v[3] = f2b(f0.w);
                    v[4] = f2b(f1.x); v[5] = f2b(f1.y); v[6] = f2b(f1.z); v[7] = f2b(f1.w);
                } else {
                    v = *(const bf16x8*)((const short*)Aptr + (size_t)gr * 128 + k0 + kg * 8);
                }
            }
            a[fm] = v;
        }
#pragma unroll
        for (int fn = 0; fn < 4; fn++)
            b[fn] = *(const bf16x8*)(WbT + (size_t)(wc + fn * 16 + lr) * 128 + k0 + kg * 8);
#pragma unroll
        for (int fm = 0; fm < 2; fm++)
#pragma unroll
            for (int fn = 0; fn < 4; fn++)
                acc[fm][fn] = __builtin_amdgcn_mfma_f32_16x16x32_bf16(
                    a[fm], b[fn], acc[fm][fn], 0, 0, 0);
    }
#pragma unroll
    for (int fm = 0; fm < 2; fm++) {
#pragma unroll
        for (int r = 0; r < 4; r++) {
            int gr = n0 + wr + fm * 16 + kg * 4 + r;
            if (gr < nrows) {
#pragma unroll
                for (int fn = 0; fn < 4; fn++) {
                    int col = wc + fn * 16 + lr;
                    outb[(size_t)gr * 128 + col] = f2b(acc[fm][fn][r]);
                }
            }
        }
    }
}

// ---------------- per-node attention coefficients (bf16 input) ----------------
__global__ void node_al(const short* __restrict__ xsb, const float* __restrict__ a_s,
                        const float* __restrict__ a_d, float* __restrict__ alsrc,
                        float* __restrict__ aldst, int n) {
    int t = blockIdx.x * blockDim.x + threadIdx.x;
    if (t >= n * 8) return;
    int node = t >> 3, h = t & 7;
    const short* xp = xsb + (size_t)node * 128 + h * 16;
    uint4 u0 = *(const uint4*)(xp);
    uint4 u1 = *(const uint4*)(xp + 8);
    unsigned w[8] = {u0.x, u0.y, u0.z, u0.w, u1.x, u1.y, u1.z, u1.w};
    float ss = 0.f, dd = 0.f;
#pragma unroll
    for (int q = 0; q < 8; q++) {
        float lo = b2f_lo(w[q]), hi = b2f_hi(w[q]);
        ss += lo * a_s[h * 16 + q * 2] + hi * a_s[h * 16 + q * 2 + 1];
        dd += lo * a_d[h * 16 + q * 2] + hi * a_d[h * 16 + q * 2 + 1];
    }
    alsrc[t] = ss;
    aldst[t] = dd;
}

// ---------------- CSR build (padded to multiples of 8 per dst) ----------------
__global__ void hist_k(const int* __restrict__ ei, int* __restrict__ cnt, int ne) {
    int e = blockIdx.x * blockDim.x + threadIdx.x;
    if (e < ne) atomicAdd(&cnt[ei[ne + e]], 1);
}

__global__ void scan1_k(const int* __restrict__ cnt, int* __restrict__ rowptr,
                        int* __restrict__ part, int n) {
    __shared__ int s[256];
    int tid = threadIdx.x;
    int i = blockIdx.x * 256 + tid;
    int v = (i < n) ? ((cnt[i] + 7) & ~7) : 0;   // padded count
    s[tid] = v; __syncthreads();
#pragma unroll
    for (int off = 1; off < 256; off <<= 1) {
        int t = (tid >= off) ? s[tid - off] : 0;
        __syncthreads();
        s[tid] += t;
        __syncthreads();
    }
    if (i < n) rowptr[i] = s[tid] - v;
    if (tid == 255) part[blockIdx.x] = s[255];
}

__global__ void scan2_k(int* __restrict__ part, int npart) {
    __shared__ int s[256];
    int tid = threadIdx.x;
    int v = (tid < npart) ? part[tid] : 0;
    s[tid] = v; __syncthreads();
#pragma unroll
    for (int off = 1; off < 256; off <<= 1) {
        int t = (tid >= off) ? s[tid - off] : 0;
        __syncthreads();
        s[tid] += t;
        __syncthreads();
    }
    if (tid < npart) part[tid] = s[tid] - v;
}

__global__ void scan3_k(int* __restrict__ rowptr, const int* __restrict__ part,
                        const int* __restrict__ cnt, int* __restrict__ cursor, int n) {
    int i = blockIdx.x * 256 + threadIdx.x;
    if (i < n) {
        int r = rowptr[i] + part[blockIdx.x];
        rowptr[i] = r;
        cursor[i] = r;
        if (i == n - 1) rowptr[n] = r + ((cnt[i] + 7) & ~7);
    }
}

// scatter: build csr_src + CSR-ordered bf16 edge attrs (pads remain 0x80808080 from memset)
__global__ void scatter_k(const int* __restrict__ ei, const float* __restrict__ eattr,
                          int* __restrict__ cursor, int* __restrict__ csr_src,
                          short* __restrict__ eatb, int ne) {
    int e = blockIdx.x * blockDim.x + threadIdx.x;
    if (e >= ne) return;
    int d = ei[ne + e];
    int p = atomicAdd(&cursor[d], 1);
    csr_src[p] = ei[e];
    const float4* ep = (const float4*)(eattr + (size_t)e * 16);
    short* op = eatb + (size_t)p * 16;
#pragma unroll
    for (int q = 0; q < 4; q++) {
        float4 v = ep[q];
        *(short4*)(op + q * 4) = make_short4(f2b(v.x), f2b(v.y), f2b(v.z), f2b(v.w));
    }
}

// ---------------- graph boundaries from sorted batch ----------------
__global__ void gbound_k(const int* __restrict__ batch, int* __restrict__ gb, int n, int g) {
    int i = blockIdx.x * 256 + threadIdx.x;
    if (i >= n) return;
    int b1 = batch[i];
    int b0 = (i == 0) ? -1 : batch[i - 1];
    for (int q = b0 + 1; q <= b1; q++) gb[q] = i;
    if (i == n - 1)
        for (int q = b1 + 1; q <= g; q++) gb[q] = n;
}

// ---------------- segmented pool: one block per graph (sorted batch), bf16 out ----------------
__global__ __launch_bounds__(256) void pools_k(const short* __restrict__ h3b,
                                               const int* __restrict__ gb,
                                               short* __restrict__ poolb) {
    __shared__ float red[128];
    int g = blockIdx.x;
    int c = threadIdx.x & 127;
    int par = threadIdx.x >> 7;   // 0/1
    int i0 = gb[g], i1 = gb[g + 1];
    float s = 0.f;
    for (int i = i0 + par; i < i1; i += 2) s += b2f_s(h3b[(size_t)i * 128 + c]);
    if (par == 1) red[c] = s;
    __syncthreads();
    if (par == 0) poolb[(size_t)g * 128 + c] = f2b(s + red[c]);
}

// ---------------- gather: fused logits + softmax-aggregate; producer-side exp ----------------
__global__ __launch_bounds__(256) void gather_k(const int* __restrict__ rowptr,
                                                const int* __restrict__ csr_src,
                                                const short* __restrict__ eatb,
                                                const float* __restrict__ aeW,
                                                const float* __restrict__ alsrc,
                                                const float* __restrict__ aldst,
                                                const short* __restrict__ xsb,
                                                const float* __restrict__ b,
                                                short* __restrict__ houtb, int n) {
    __shared__ float sAe[128];
    if (threadIdx.x < 128) sAe[threadIdx.x] = aeW[threadIdx.x];
    __syncthreads();
    int dst = blockIdx.x * 4 + (threadIdx.x >> 6);
    if (dst >= n) return;
    const int lane = threadIdx.x & 63;
    const int h  = lane >> 3;   // consumer head
    const int pe = lane >> 3;   // producer edge
    const int ph = lane & 7;    // producer head
    const float L2E = 1.44269504f;
    int p0 = rowptr[dst], p1 = rowptr[dst + 1];
    float ald_p = aldst[dst * 8 + ph];   // producer-role dst coefficient
    float den = 0.f, acc0 = 0.f, acc1 = 0.f;
    const int nfull = (p1 - p0) >> 3;   // padded: no tail
    int p = p0;
    int svo = 0; unsigned w = 0;
    if (nfull > 0) {
        svo = csr_src[p + pe];
        w = *(const unsigned*)(eatb + (size_t)(p + pe) * 16 + ph * 2);
    }
    for (int c = 0; c < nfull; c++) {
        int csv = svo; unsigned cw = w;
        int pn = p + 8;
        if (c + 1 < nfull) {                         // prefetch next chunk
            svo = csr_src[pn + pe];
            w = *(const unsigned*)(eatb + (size_t)(pn + pe) * 16 + ph * 2);
        }
        // ---- producer: finished exp weight for (edge pe, head ph) ----
        int sc = csv < 0 ? 0 : csv;
        float pal = alsrc[sc * 8 + ph];
#pragma unroll
        for (int k = 0; k < 8; k++) {
            unsigned u = __shfl(cw, pe * 8 + k);
            pal += b2f_lo(u) * sAe[k * 16 + ph] + b2f_hi(u) * sAe[k * 16 + 8 + ph];
        }
        float lg = pal + ald_p;
        lg = lg > 0.f ? lg : 0.2f * lg;              // leaky_relu(0.2)
        float pex = exp2f(lg * L2E);
        if (csv < 0) pex = 0.f;                      // pad edge contributes nothing
        // ---- rows ----
        int t0 = __shfl(csv, 0),  t1 = __shfl(csv, 8),  t2 = __shfl(csv, 16), t3 = __shfl(csv, 24);
        int t4 = __shfl(csv, 32), t5 = __shfl(csv, 40), t6 = __shfl(csv, 48), t7 = __shfl(csv, 56);
        t0 = t0 < 0 ? 0 : t0;  t1 = t1 < 0 ? 0 : t1;
        t2 = t2 < 0 ? 0 : t2;  t3 = t3 < 0 ? 0 : t3;
        t4 = t4 < 0 ? 0 : t4;  t5 = t5 < 0 ? 0 : t5;
        t6 = t6 < 0 ? 0 : t6;  t7 = t7 < 0 ? 0 : t7;
        unsigned v0 = *(const unsigned*)(xsb + (size_t)t0 * 128 + lane * 2);
        unsigned v1 = *(const unsigned*)(xsb + (size_t)t1 * 128 + lane * 2);
        unsigned v2 = *(const unsigned*)(xsb + (size_t)t2 * 128 + lane * 2);
        unsigned v3 = *(const unsigned*)(xsb + (size_t)t3 * 128 + lane * 2);
        unsigned v4 = *(const unsigned*)(xsb + (size_t)t4 * 128 + lane * 2);
        unsigned v5 = *(const unsigned*)(xsb + (size_t)t5 * 128 + lane * 2);
        unsigned v6 = *(const unsigned*)(xsb + (size_t)t6 * 128 + lane * 2);
        unsigned v7 = *(const unsigned*)(xsb + (size_t)t7 * 128 + lane * 2);
        unsigned vv[8] = {v0, v1, v2, v3, v4, v5, v6, v7};
        // ---- consumer: weighted accumulate with ready weights ----
#pragma unroll
        for (int i = 0; i < 8; i++) {
            float ex = __shfl(pex, i * 8 + h);
            den  += ex;
            acc0 += b2f_lo(vv[i]) * ex;
            acc1 += b2f_hi(vv[i]) * ex;
        }
        p = pn;
    }
    float inv = 1.f / (den + 1e-16f);
    const float2 bb = *(const float2*)(b + lane * 2);
    unsigned o = pack2(f2b(acc0 * inv + bb.x), f2b(acc1 * inv + bb.y));
    *(unsigned*)(houtb + (size_t)dst * 128 + lane * 2) = o;
}

// ---------------- Wl1 [512(k),512(c)] f32 -> Wl1T [c][k] bf16 ----------------
__global__ void wl1t_k(const float* __restrict__ Wl1, short* __restrict__ Wl1T) {
    int idx = blockIdx.x * blockDim.x + threadIdx.x;   // 262144
    int k = idx >> 9, c = idx & 511;
    Wl1T[(size_t)c * 512 + k] = f2b(Wl1[idx]);
}

__global__ void init_out(float* __restrict__ out, const float* __restrict__ bl2, int n) {
    int t = blockIdx.x * blockDim.x + threadIdx.x;
    if (t < n) out[t] = bl2[0];
}

// ---------------- fused final MLP via bf16 MFMA: BK=128 double-buffer ----------------
__global__ __launch_bounds__(256) void final_mfma(
    const short* __restrict__ h1, const short* __restrict__ h2,
    const short* __restrict__ h3, const short* __restrict__ poolb,
    const int* __restrict__ batch, const short* __restrict__ Wl1T,
    const float* __restrict__ bl1, const float* __restrict__ Wl2,
    float* __restrict__ out, int nrows)
{
    __shared__ short Abuf[2][16 * 64 * 8];   // 2 x 16 KB: [buf][slot][row-lane][8]
    __shared__ int   sBatch[64];
    const int tid = threadIdx.x;
    const int n0 = blockIdx.x * 64;
    const int j0 = blockIdx.y * 256;
    const int wid = tid >> 6, lane = tid & 63;
    const int lr = lane & 15, kg = lane >> 4;

    if (tid < 64) {
        int gr = n0 + tid;
        sBatch[tid] = (gr < nrows) ? batch[gr] : 0;
    }
    __syncthreads();

    const short* seg_base[4] = {h1, h2, h3, poolb};

    auto STAGE = [&](int t) {
        const short* base = seg_base[t];
        int gr = n0 + lane;
        int grow = (t == 3) ? sBatch[lane] : ((gr < nrows) ? gr : 0);
        const short* rowp = base + (size_t)grow * 128;
#pragma unroll
        for (int q = 0; q < 4; q++) {
            const short* src = rowp + q * 32 + wid * 8;
#if __has_builtin(__builtin_amdgcn_global_load_lds)
            __builtin_amdgcn_global_load_lds(
                (const __attribute__((address_space(1))) unsigned int*)src,
                (__attribute__((address_space(3))) unsigned int*)
                    &Abuf[t & 1][((q * 4 + wid) * 64 + lane) * 8],
                16, 0, 0);
#else
            uint4 v = *(const uint4*)src;
            *(uint4*)(&Abuf[t & 1][((q * 4 + wid) * 64 + lane) * 8]) = v;
#endif
        }
    };

    f32x4 acc[4][4] = {};

    STAGE(0);
    __syncthreads();   // segment 0 landed (full drain)
#pragma unroll
    for (int t = 0; t < 4; t++) {
        if (t < 3) STAGE(t + 1);   // hides under this segment's 64 MFMAs
#pragma unroll
        for (int ks = 0; ks < 4; ks++) {
            bf16x8 a[4], b[4];
#pragma unroll
            for (int fn = 0; fn < 4; fn++)
                b[fn] = *(const bf16x8*)(Wl1T + (size_t)(j0 + wid * 64 + fn * 16 + lr) * 512
                                         + t * 128 + ks * 32 + kg * 8);
#pragma unroll
            for (int fm = 0; fm < 4; fm++)
                a[fm] = *(const bf16x8*)(&Abuf[t & 1][((ks * 4 + kg) * 64 + fm * 16 + lr) * 8]);
#pragma unroll
            for (int fm = 0; fm < 4; fm++)
#pragma unroll
                for (int fn = 0; fn < 4; fn++)
                    acc[fm][fn] = __builtin_amdgcn_mfma_f32_16x16x32_bf16(
                        a[fm], b[fn], acc[fm][fn], 0, 0, 0);
        }
        if (t < 3) __syncthreads();   // drains STAGE(t+1); buffer reads done
    }

    float w2[4], b1c[4];
#pragma unroll
    for (int fn = 0; fn < 4; fn++) {
        int c = j0 + wid * 64 + fn * 16 + lr;
        w2[fn]  = Wl2[c];
        b1c[fn] = bl1[c];
    }

#pragma unroll
    for (int fm = 0; fm < 4; fm++) {
#pragma unroll
        for (int r = 0; r < 4; r++) {
            float s = 0.f;
#pragma unroll
            for (int fn = 0; fn < 4; fn++) {
                float z = acc[fm][fn][r] + b1c[fn];
                z = z > 0.f ? z : 0.01f * z;
                s += z * w2[fn];
            }
            s += __shfl_xor(s, 1);
            s += __shfl_xor(s, 2);
            s += __shfl_xor(s, 4);
            s += __shfl_xor(s, 8);
            if (lr == 0) {
                int gr = n0 + fm * 16 + kg * 4 + r;
                if (gr < nrows) atomicAdd(out + gr, s);
            }
        }
    }
}

extern "C" void kernel_launch(void* const* d_in, const int* in_sizes, int n_in,
                              void* d_out, int out_size, void* d_ws, size_t ws_size,
                              hipStream_t stream) {
    const float* x     = (const float*)d_in[0];
    const int*   ei    = (const int*)d_in[1];
    const float* eattr = (const float*)d_in[2];
    const int*   batch = (const int*)d_in[3];
    const float* W[3]   = {(const float*)d_in[4],  (const float*)d_in[10], (const float*)d_in[16]};
    const float* We[3]  = {(const float*)d_in[5],  (const float*)d_in[11], (const float*)d_in[17]};
    const float* as_[3] = {(const float*)d_in[6],  (const float*)d_in[12], (const float*)d_in[18]};
    const float* ad_[3] = {(const float*)d_in[7],  (const float*)d_in[13], (const float*)d_in[19]};
    const float* ae_[3] = {(const float*)d_in[8],  (const float*)d_in[14], (const float*)d_in[20]};
    const float* b_[3]  = {(const float*)d_in[9],  (const float*)d_in[15], (const float*)d_in[21]};
    const float* Wl1 = (const float*)d_in[22];
    const float* bl1 = (const float*)d_in[23];
    const float* Wl2 = (const float*)d_in[24];
    const float* bl2 = (const float*)d_in[25];

    const int N = N_NODES, E = N_EDGES, G = N_GRAPH;

    float* ws    = (float*)d_ws;
    float* alsrc = ws;                          // N*8
    float* aldst = alsrc + (size_t)N * 8;       // N*8
    float* aeW3  = aldst + (size_t)N * 8;       // 3*128
    short* xsb   = (short*)(aeW3 + 384);        // N*128 bf16 (layer GEMM out)
    short* hb0   = xsb + (size_t)N * 128;       // N*128 bf16
    short* hb1   = hb0 + (size_t)N * 128;
    short* hb2   = hb1 + (size_t)N * 128;
    short* hb[3] = {hb0, hb1, hb2};
    short* poolb = hb2 + (size_t)N * 128;       // G*128 bf16
    short* wbt   = poolb + (size_t)G * 128;     // 3 x 128*128 bf16
    short* wl1t  = wbt + 3 * 16384;             // 512*512 bf16
    short* eatb  = wl1t + 262144;               // EPAD*16 bf16
    int*   cnt     = (int*)(eatb + (size_t)EPAD * 16);  // N
    int*   rowptr  = cnt + N;                   // N+1
    int*   cursor  = rowptr + N + 1;            // N
    int*   part    = cursor + N;                // 256
    int*   gb      = part + 256;                // G+1
    int*   csr_src = gb + G + 1;                // EPAD

    // ---- once per call: bf16 conversions + padded dst-CSR + graph bounds ----
    wbt3_k<<<192, 256, 0, stream>>>(W[0], W[1], W[2], wbt);
    wl1t_k<<<1024, 256, 0, stream>>>(Wl1, wl1t);
    aew3_k<<<3, 128, 0, stream>>>(We[0], ae_[0], We[1], ae_[1], We[2], ae_[2], aeW3);
    hipMemsetAsync(cnt, 0, (size_t)N * sizeof(int), stream);
    hipMemsetAsync(csr_src, 0x80, (size_t)EPAD * sizeof(int), stream);  // pads negative
    hist_k<<<(E + 255) / 256, 256, 0, stream>>>(ei, cnt, E);
    const int nblk = (N + 255) / 256;   // 196
    scan1_k<<<nblk, 256, 0, stream>>>(cnt, rowptr, part, N);
    scan2_k<<<1, 256, 0, stream>>>(part, nblk);
    scan3_k<<<nblk, 256, 0, stream>>>(rowptr, part, cnt, cursor, N);
    scatter_k<<<(E + 255) / 256, 256, 0, stream>>>(ei, eattr, cursor, csr_src, eatb, E);
    gbound_k<<<nblk, 256, 0, stream>>>(batch, gb, N, G);

    for (int l = 0; l < 3; l++) {
        if (l == 0)
            gemm_mfma<true><<<(N + 63) / 64, 256, 0, stream>>>(x, wbt, xsb, N);
        else
            gemm_mfma<false><<<(N + 63) / 64, 256, 0, stream>>>(hb[l - 1], wbt + l * 16384,
                                                                xsb, N);
        node_al<<<(N * 8 + 255) / 256, 256, 0, stream>>>(xsb, as_[l], ad_[l], alsrc, aldst, N);
        gather_k<<<(N + 3) / 4, 256, 0, stream>>>(rowptr, csr_src, eatb, aeW3 + l * 128,
                                                  alsrc, aldst, xsb, b_[l], hb[l], N);
    }
    pools_k<<<G, 256, 0, stream>>>(hb[2], gb, poolb);

    init_out<<<(N + 255) / 256, 256, 0, stream>>>((float*)d_out, bl2, N);
    dim3 fg((N + 63) / 64, 2);
    final_mfma<<<fg, 256, 0, stream>>>(hb[0], hb[1], hb[2], poolb, batch,
                                       wl1t, bl1, Wl2, (float*)d_out, N);
}